// Round 3
// baseline (959.423 us; speedup 1.0000x reference)
//
#include <hip/hip_runtime.h>
#include <hip/hip_bf16.h>
#include <stdint.h>

// ---------------------------------------------------------------------------
// UnitaryExpert: out = rot_theta(x @ U1^T) @ U2^T + passthrough
// U = I + 2A + 2A^2 + 2A^3 + 2A^4 + 2A^5 + A^6,  A = 0.5(W - W^T)
// R3 algebra: U = (I+A)^2 (I + B + B^2) = G * F,   B := A^2 = -S1
//   S1 = A*A^T  (BT gemm)        epilogue: Bbf=bf16(-S1), Gbf=bf16(I+2A-S1)
//   S2 = B*B^T  (BT gemm)        epilogue: Fbf=bf16(I - S1 + S2)
//   U  = G*F^T  (F symmetric)    epilogue: Ubf=bf16(acc)
// Big GEMMs (65536x1024x1024): gemm256 (256^2 tile, BK=64, 8 waves, 4-phase,
// T1 XCD swizzle + T2 LDS XOR-swizzle + T4 counted vmcnt + T5 setprio).
// R3 schedule: ALL 8 next-tile stages issued in phase 1, gate vmcnt(8)
// (youngest gated load gets ~3.5 phases of cover vs ~1 phase in R2).
// ---------------------------------------------------------------------------

#define MM (1024 * 1024)

typedef __attribute__((ext_vector_type(4))) float f32x4;
typedef __attribute__((ext_vector_type(8))) short bf16x8;

__device__ __forceinline__ ushort f2bf(float f) {  // round-to-nearest-even
  uint32_t u = __builtin_bit_cast(uint32_t, f);
  u += 0x7FFFu + ((u >> 16) & 1u);
  return (ushort)(u >> 16);
}
__device__ __forceinline__ float bf2f(ushort h) {
  uint32_t u = ((uint32_t)h) << 16;
  return __builtin_bit_cast(float, u);
}

__device__ __forceinline__ void gld_lds16(const ushort* g, ushort* l) {
  // async 16B/lane global->LDS; LDS dest = wave-uniform base + lane*16
  __builtin_amdgcn_global_load_lds(
      (const __attribute__((address_space(1))) unsigned int*)g,
      (__attribute__((address_space(3))) unsigned int*)l, 16, 0, 0);
}

// ===========================================================================
// gemm256: C[m,n] = sum_k X[m,k]*Y[n,k], X:[M,K], Y:[N,K] bf16 row-major.
// BM=BN=256, BK=64, 512 thr (8 waves, 2M x 4N), per-wave out 128x64.
// LDS 128 KiB: 2 bufs x (A[256][64] | B[256][64]) bf16, XOR-swizzled
// (byte ^= (row&7)<<4) via pre-swizzled global source + swizzled ds_read.
// Per K-tile: 4 phases (C-quadrants). Phase 1 issues ALL next-tile stages
// (8 gld_lds) then counted vmcnt(8); phases 2-4 pure ds_read+MFMA.
// mode 1: pair-rotation epilogue -> bf16 o16 ; mode 2: +passthrough -> f32 o32
// Requires: N==1024 (grid.x==4), M%256==0, K%64==0.
// ===========================================================================
#define STAGE(GS, LB, BUF, H, KT)                                      \
  do {                                                                 \
    const ushort* g_ = (GS) + (size_t)((H)*128) * K + (size_t)(KT)*64; \
    ushort* d_ = (LB) + (BUF)*32768 + (H)*128 * 64;                    \
    gld_lds16(g_, d_);                                                 \
    gld_lds16(g_ + (size_t)64 * K, d_ + 64 * 64);                      \
  } while (0)

#define LDA(MH, BUF)                                                        \
  do {                                                                      \
    _Pragma("unroll") for (int ti = 0; ti < 4; ++ti) {                      \
      const ushort* p_ = rdA + (BUF)*32768 + ((MH)*64 + ti * 16 + lr) * 64; \
      af[ti][0] = *(const bf16x8*)(p_ + (pcol0 >> 1));                      \
      af[ti][1] = *(const bf16x8*)(p_ + (pcol1 >> 1));                      \
    }                                                                       \
  } while (0)

#define LDB(NH, BUF)                                                        \
  do {                                                                      \
    _Pragma("unroll") for (int tj = 0; tj < 2; ++tj) {                      \
      const ushort* p_ = rdB + (BUF)*32768 + ((NH)*32 + tj * 16 + lr) * 64; \
      bfr[tj][0] = *(const bf16x8*)(p_ + (pcol0 >> 1));                     \
      bfr[tj][1] = *(const bf16x8*)(p_ + (pcol1 >> 1));                     \
    }                                                                       \
  } while (0)

#define MFMA16(MH, NH)                                                  \
  do {                                                                  \
    __builtin_amdgcn_s_setprio(1);                                      \
    _Pragma("unroll") for (int m_ = 0; m_ < 4; ++m_)                    \
    _Pragma("unroll") for (int n_ = 0; n_ < 2; ++n_)                    \
    _Pragma("unroll") for (int ks_ = 0; ks_ < 2; ++ks_)                 \
      acc[(MH)*4 + m_][(NH)*2 + n_] =                                   \
          __builtin_amdgcn_mfma_f32_16x16x32_bf16(                      \
              af[m_][ks_], bfr[n_][ks_], acc[(MH)*4 + m_][(NH)*2 + n_], \
              0, 0, 0);                                                 \
    __builtin_amdgcn_s_setprio(0);                                      \
  } while (0)

#define CFENCE asm volatile("" ::: "memory")
#define SBAR                           \
  do {                                 \
    CFENCE;                            \
    __builtin_amdgcn_s_barrier();      \
    __builtin_amdgcn_sched_barrier(0); \
  } while (0)

__global__ __launch_bounds__(512, 2) void gemm256(
    const ushort* __restrict__ X, const ushort* __restrict__ Y,
    float* __restrict__ o32, ushort* __restrict__ o16, int M, int N, int K,
    int mode, const float* __restrict__ theta_p,
    const float* __restrict__ sums) {
  extern __shared__ ushort lds[];  // [buf][A:16384 | B:16384] ushorts

  const int tid = threadIdx.x;
  const int wave = tid >> 6, lane = tid & 63;

  // T1: XCD-chunked bijective swizzle (nwg = 1024, multiple of 8)
  const int nwg = gridDim.x * gridDim.y;
  const int lin = blockIdx.y * gridDim.x + blockIdx.x;
  const int wgid = (lin & 7) * (nwg >> 3) + (lin >> 3);
  const int bn = wgid & 3;  // gridDim.x == 4 (N = 1024)
  const int bm = wgid >> 2;

  const int wrow = wave >> 2;  // 0..1
  const int wcol = wave & 3;   // 0..3

  // staging: thread covers row srow (of 64-row slab), 16B at swizzled k-col
  const int srow = wave * 8 + (lane >> 3);
  const int scol = (((lane & 7) ^ ((lane >> 3) & 7)) << 3);  // elems
  const ushort* Xs = X + (size_t)(bm * 256 + srow) * K + scol;
  const ushort* Ys = Y + (size_t)(bn * 256 + srow) * K + scol;
  ushort* stA = lds + wave * 8 * 64;  // + buf*32768 + h*128*64
  ushort* stB = lds + 16384 + wave * 8 * 64;

  // reads: row-local XOR swizzle; (row&7) == (lr&7) since bases are %8==0
  const int lr = lane & 15;
  const int kqb = (lane >> 4) << 4;  // byte 0/16/32/48
  const int swz = (lr & 7) << 4;
  const int pcol0 = (0 + kqb) ^ swz;   // bytes, k-slice 0
  const int pcol1 = (64 + kqb) ^ swz;  // bytes, k-slice 1
  const ushort* rdA = lds + wrow * 128 * 64;
  const ushort* rdB = lds + 16384 + wcol * 64 * 64;

  f32x4 acc[8][4] = {};
  bf16x8 af[4][2], bfr[2][2];

  const int NT = K >> 6;

  // prologue: stage tile 0 -> buf0 (8 loads/wave)
  STAGE(Xs, stA, 0, 0, 0);
  STAGE(Xs, stA, 0, 1, 0);
  STAGE(Ys, stB, 0, 0, 0);
  STAGE(Ys, stB, 0, 1, 0);

  for (int t = 0; t < NT; ++t) {
    const int cur = t & 1, nxt = cur ^ 1;
    // -- phase 1: quadrant (0,0); issue ALL of tile t+1, gate tile t
    if (t + 1 < NT) {
      STAGE(Xs, stA, nxt, 0, t + 1);
      STAGE(Xs, stA, nxt, 1, t + 1);
      STAGE(Ys, stB, nxt, 0, t + 1);
      STAGE(Ys, stB, nxt, 1, t + 1);
      asm volatile("s_waitcnt vmcnt(8)" ::: "memory");
    } else {
      asm volatile("s_waitcnt vmcnt(0)" ::: "memory");
    }
    SBAR;
    LDA(0, cur);
    LDB(0, cur);
    MFMA16(0, 0);
    SBAR;
    // -- phase 2: (0,1)
    LDB(1, cur);
    SBAR;
    MFMA16(0, 1);
    SBAR;
    // -- phase 3: (1,1)
    LDA(1, cur);
    SBAR;
    MFMA16(1, 1);
    SBAR;
    // -- phase 4: (1,0)
    LDB(0, cur);
    SBAR;
    MFMA16(1, 0);
    SBAR;
  }

  // epilogue: C/D layout col = lane&15, row = (lane>>4)*4 + reg
  const int q4 = (lane >> 4) * 4;
  const int rbase = bm * 256 + wrow * 128;
  const int cbase = bn * 256 + wcol * 64;
  if (mode == 1) {
    float th = *theta_p, s, c;
    __sincosf(th, &s, &c);
    const float ssgn = (lane & 1) ? s : -s;
#pragma unroll
    for (int fi = 0; fi < 8; ++fi)
#pragma unroll
      for (int r = 0; r < 4; ++r) {
        const size_t row = (size_t)(rbase + fi * 16 + q4 + r);
        ushort* Orow = o16 + row * N;
#pragma unroll
        for (int fj = 0; fj < 4; ++fj) {
          float v = acc[fi][fj][r];
          float w = __shfl_xor(v, 1);
          Orow[cbase + fj * 16 + lr] = f2bf(c * v + ssgn * w);
        }
      }
  } else {
    const float pt = 1e-6f * (sums[0] * (1.0f / 1048576.0f) +
                              sums[1] * (1.0f / 1048576.0f) + *theta_p);
#pragma unroll
    for (int fi = 0; fi < 8; ++fi)
#pragma unroll
      for (int r = 0; r < 4; ++r) {
        const size_t row = (size_t)(rbase + fi * 16 + q4 + r);
        float* Orow = o32 + row * N;
#pragma unroll
        for (int fj = 0; fj < 4; ++fj)
          Orow[cbase + fj * 16 + lr] = acc[fi][fj][r] + pt;
      }
  }
}

// ---------------------------------------------------------------------------
// BT GEMM (m97 structure) for the small 1024^3 chain. z in {0,1} selects
// matrix (offset mi*MM on X, Y and outputs).
// mode 3: o32 = acc (S1) ; o16 = bf16(-acc) (Bbf);
//         o16b = bf16(I + 2*A - acc) (Gbf), A bf16 via auxb
// mode 4: o16 = bf16(I - auxf + acc) (Fbf), auxf = S1 fp32
// mode 5: o16 = bf16(acc) (Ubf)
// ---------------------------------------------------------------------------
__global__ __launch_bounds__(256, 2) void gemm_bt(
    const ushort* __restrict__ X0, const ushort* __restrict__ Y0,
    float* __restrict__ o32, ushort* __restrict__ o16,
    ushort* __restrict__ o16b, const float* __restrict__ auxf,
    const ushort* __restrict__ auxb, int M, int N, int K, int mode,
    const float* __restrict__ theta_p, const float* __restrict__ sums) {
  __shared__ ushort lA[128 * 32];
  __shared__ ushort lB[128 * 32];

  const int tid = threadIdx.x;
  const int wave = tid >> 6, lane = tid & 63;
  const int mi = blockIdx.z & 1;

  const int nwg = gridDim.x * gridDim.y;
  const int lin = blockIdx.y * gridDim.x + blockIdx.x;
  const int swzb = (lin & 7) * (nwg >> 3) + (lin >> 3);
  const int bn = swzb & 7;  // gridDim.x == 8 always
  const int bm = swzb >> 3;

  const ushort* X = X0 + (size_t)mi * MM;
  const ushort* Y = Y0 + (size_t)mi * MM;

  const ushort* Xg = X + (size_t)(bm * 128 + (tid >> 2)) * K + (tid & 3) * 8;
  const ushort* Yg = Y + (size_t)(bn * 128 + (tid >> 2)) * K + (tid & 3) * 8;
  ushort* lAw = lA + wave * 512;
  ushort* lBw = lB + wave * 512;

  const int wm = (wave & 1) * 64;
  const int wn = (wave >> 1) * 64;
  const int lr = lane & 15;
  const int kq = (lane >> 4) * 8;

  f32x4 acc[4][4] = {};

  for (int k0 = 0; k0 < K; k0 += 32) {
    __syncthreads();
    gld_lds16(Xg + k0, lAw);
    gld_lds16(Xg + k0 + (size_t)64 * K, lAw + 64 * 32);
    gld_lds16(Yg + k0, lBw);
    gld_lds16(Yg + k0 + (size_t)64 * K, lBw + 64 * 32);
    __syncthreads();

    bf16x8 afv[4], bfg[4];
#pragma unroll
    for (int t = 0; t < 4; ++t) {
      afv[t] = *(const bf16x8*)(lA + (wm + t * 16 + lr) * 32 + kq);
      bfg[t] = *(const bf16x8*)(lB + (wn + t * 16 + lr) * 32 + kq);
    }
#pragma unroll
    for (int ti = 0; ti < 4; ++ti)
#pragma unroll
      for (int tj = 0; tj < 4; ++tj)
        acc[ti][tj] = __builtin_amdgcn_mfma_f32_16x16x32_bf16(
            afv[ti], bfg[tj], acc[ti][tj], 0, 0, 0);
  }

  const int q4 = (lane >> 4) * 4;
  const size_t zoff = (size_t)mi * MM;
  float* O = (mode == 3) ? o32 + zoff : nullptr;
  ushort* P0 = o16 + zoff;
  ushort* P1 = (mode == 3) ? o16b + zoff : nullptr;
  const float* Ax = (mode == 4) ? auxf + zoff : nullptr;
  const ushort* Ab = (mode == 3) ? auxb + zoff : nullptr;
#pragma unroll
  for (int ti = 0; ti < 4; ++ti)
#pragma unroll
    for (int r = 0; r < 4; ++r) {
      const int row = bm * 128 + wm + ti * 16 + q4 + r;
      const size_t base = (size_t)row * N;
#pragma unroll
      for (int tj = 0; tj < 4; ++tj) {
        const int col = bn * 128 + wn + tj * 16 + lr;
        const float v = acc[ti][tj][r];
        const float diag = (row == col) ? 1.f : 0.f;
        if (mode == 3) {
          O[base + col] = v;
          P0[base + col] = f2bf(-v);
          P1[base + col] = f2bf(diag + 2.f * bf2f(Ab[base + col]) - v);
        } else if (mode == 4) {
          P0[base + col] = f2bf(diag - Ax[base + col] + v);
        } else {
          P0[base + col] = f2bf(v);
        }
      }
    }
}

// ---------------------------------------------------------------------------
// A = 0.5(W - W^T) -> bf16, fused sum(W) reduction (for passthrough mean).
// ---------------------------------------------------------------------------
__global__ __launch_bounds__(256) void prep_a(const float* __restrict__ W1,
                                              const float* __restrict__ W2,
                                              ushort* __restrict__ Abf,
                                              float* __restrict__ sums) {
  __shared__ float sT[32][33];
  const int z = blockIdx.z;
  const float* W = z ? W2 : W1;
  ushort* A = Abf + (size_t)z * MM;
  const int r0 = blockIdx.y * 32, c0 = blockIdx.x * 32;
  const int x = threadIdx.x, y = threadIdx.y;

#pragma unroll
  for (int k = 0; k < 4; ++k)
    sT[y + 8 * k][x] = W[(size_t)(c0 + y + 8 * k) * 1024 + r0 + x];
  __syncthreads();

  float lsum = 0.f;
#pragma unroll
  for (int k = 0; k < 4; ++k) {
    int i = y + 8 * k;
    float w = W[(size_t)(r0 + i) * 1024 + c0 + x];
    lsum += w;
    A[(size_t)(r0 + i) * 1024 + c0 + x] = f2bf(0.5f * (w - sT[x][i]));
  }
#pragma unroll
  for (int off = 32; off > 0; off >>= 1) lsum += __shfl_down(lsum, off);
  if (((y * 32 + x) & 63) == 0) atomicAdd(&sums[z], lsum);
}

// x fp32 -> bf16, vectorized (float4 per thread)
__global__ __launch_bounds__(256) void cvt_x(const float* __restrict__ x,
                                             ushort* __restrict__ xb) {
  const size_t i = (size_t)blockIdx.x * 256 + threadIdx.x;
  float4 v = ((const float4*)x)[i];
  ushort4 o;
  o.x = f2bf(v.x);
  o.y = f2bf(v.y);
  o.z = f2bf(v.z);
  o.w = f2bf(v.w);
  ((ushort4*)xb)[i] = o;
}

extern "C" void kernel_launch(void* const* d_in, const int* in_sizes, int n_in,
                              void* d_out, int out_size, void* d_ws,
                              size_t ws_size, hipStream_t stream) {
  const float* xin = (const float*)d_in[0];
  const float* w1 = (const float*)d_in[1];
  const float* w2 = (const float*)d_in[2];
  const float* th = (const float*)d_in[3];
  float* out = (float*)d_out;

  // workspace carve (all 256B-aligned)
  char* w = (char*)d_ws;
  float* sums = (float*)w;                   // 8 B
  ushort* Abf = (ushort*)(w + 256);          // 4 MB
  ushort* Bbf = Abf + 2 * MM;                // 4 MB
  ushort* Gbf = Bbf + 2 * MM;                // 4 MB
  ushort* Fbf = Gbf + 2 * MM;                // 4 MB
  ushort* Ubf = Fbf + 2 * MM;                // 4 MB (U1, U2)
  float* S1 = (float*)(Ubf + 2 * MM);        // 8 MB
  ushort* xbf = (ushort*)(S1 + 2 * MM);      // 128 MB
  ushort* hbf = xbf + (size_t)65536 * 1024;  // 128 MB

  static bool inited = false;
  if (!inited) {
    (void)hipFuncSetAttribute((const void*)gemm256,
                              hipFuncAttributeMaxDynamicSharedMemorySize,
                              131072);
    inited = true;
  }

  hipMemsetAsync(sums, 0, 2 * sizeof(float), stream);

  prep_a<<<dim3(32, 32, 2), dim3(32, 8), 0, stream>>>(w1, w2, Abf, sums);
  cvt_x<<<65536, 256, 0, stream>>>(xin, xbf);

  // S1 = A*A^T ; fused: Bbf = bf16(-S1), Gbf = bf16(I + 2A - S1)
  gemm_bt<<<dim3(8, 8, 2), 256, 0, stream>>>(Abf, Abf, S1, Bbf, Gbf, nullptr,
                                             Abf, 1024, 1024, 1024, 3, th,
                                             sums);
  // S2 = B*B^T = B^2 ; fused: Fbf = bf16(I - S1 + S2)
  gemm_bt<<<dim3(8, 8, 2), 256, 0, stream>>>(Bbf, Bbf, nullptr, Fbf, nullptr,
                                             S1, nullptr, 1024, 1024, 1024, 4,
                                             th, sums);
  // U = G*F^T (F symmetric) ; fused: Ubf = bf16(U)
  gemm_bt<<<dim3(8, 8, 2), 256, 0, stream>>>(Gbf, Fbf, nullptr, Ubf, nullptr,
                                             nullptr, nullptr, 1024, 1024,
                                             1024, 5, th, sums);

  // h = rot_theta(x @ U1^T) -> bf16   (256^2-tile kernel)
  gemm256<<<dim3(4, 256, 1), 512, 131072, stream>>>(
      xbf, Ubf, nullptr, hbf, 65536, 1024, 1024, 1, th, sums);
  // out = h @ U2^T + passthrough -> fp32
  gemm256<<<dim3(4, 256, 1), 512, 131072, stream>>>(
      hbf, Ubf + MM, out, nullptr, 65536, 1024, 1024, 2, th, sums);
}

// Round 4
// 932.050 us; speedup vs baseline: 1.0294x; 1.0294x over previous
//
#include <hip/hip_runtime.h>
#include <hip/hip_bf16.h>
#include <stdint.h>

// ---------------------------------------------------------------------------
// UnitaryExpert: out = rot_theta(x @ U1^T) @ U2^T + passthrough
// U = I + 2A + 2A^2 + 2A^3 + 2A^4 + 2A^5 + A^6,  A = 0.5(W - W^T)
// Algebra: U = (I+A)^2 (I + B + B^2) = G * F,   B := A^2 = -S1
//   S1 = A*A^T  (BT gemm)        epilogue: Bbf=bf16(-S1), Gbf=bf16(I+2A-S1)
//   S2 = B*B^T  (BT gemm)        epilogue: Fbf=bf16(I - S1 + S2)
//   U  = G*F^T  (F symmetric)    epilogue: Ubf=bf16(acc)
// R4 gemm256 (big 65536x1024x1024 GEMMs): BK=32, THREE LDS buffers (96 KiB),
// ONE barrier per K-tile, stage 2 tiles ahead, counted vmcnt(4) gate.
// 3 buffers => staging never writes a buffer being read => no mid-tile
// barriers => compiler's fine-grained lgkmcnt interleave + wave self-pacing
// overlap LDS reads with MFMA (R2/R3's 8-barriers/K-tile forced them serial).
// [256][32] row-major LDS is bank-uniform for the 16x16x32 frag read
// (row stride = 64B = 16 banks keeps row-parity in the bank index) => no
// swizzle needed, staging stays linear.
// ---------------------------------------------------------------------------

#define MM (1024 * 1024)

typedef __attribute__((ext_vector_type(4))) float f32x4;
typedef __attribute__((ext_vector_type(8))) short bf16x8;

__device__ __forceinline__ ushort f2bf(float f) {  // round-to-nearest-even
  uint32_t u = __builtin_bit_cast(uint32_t, f);
  u += 0x7FFFu + ((u >> 16) & 1u);
  return (ushort)(u >> 16);
}
__device__ __forceinline__ float bf2f(ushort h) {
  uint32_t u = ((uint32_t)h) << 16;
  return __builtin_bit_cast(float, u);
}

__device__ __forceinline__ void gld_lds16(const ushort* g, ushort* l) {
  // async 16B/lane global->LDS; LDS dest = wave-uniform base + lane*16
  __builtin_amdgcn_global_load_lds(
      (const __attribute__((address_space(1))) unsigned int*)g,
      (__attribute__((address_space(3))) unsigned int*)l, 16, 0, 0);
}

#define SBAR                           \
  do {                                 \
    asm volatile("" ::: "memory");     \
    __builtin_amdgcn_s_barrier();      \
    __builtin_amdgcn_sched_barrier(0); \
  } while (0)

// ===========================================================================
// gemm256: C[m,n] = sum_k X[m,k]*Y[n,k], X:[M,K], Y:[N,K] bf16 row-major.
// BM=BN=256, BK=32, 512 thr (8 waves, 2M x 4N), per-wave out 128x64.
// LDS 96 KiB: 3 bufs x (A[256][32] | B[256][32]) bf16, linear (no swizzle).
// Per K-tile t: {barrier; stage tile t+2 (4 gld_lds/wave); 12 ds_read_b128;
// 32 MFMA 16x16x32 (setprio-wrapped, compiler-interleaved lgkm);
// vmcnt(4) gate (completes tile t+1, leaves t+2's 4 loads in flight)}.
// mode 1: pair-rotation epilogue -> bf16 o16 ; mode 2: +passthrough -> f32 o32
// Requires: N==1024 (grid.x==4), M%256==0, K%32==0, K>=64.
// ===========================================================================
#define STAGE4(BO, KT)                                             \
  do {                                                             \
    gld_lds16(Xs + (KT)*32, stW + (BO));                           \
    gld_lds16(Xs + (KT)*32 + (size_t)128 * K, stW + (BO) + 4096);  \
    gld_lds16(Ys + (KT)*32, stW + (BO) + 8192);                    \
    gld_lds16(Ys + (KT)*32 + (size_t)128 * K, stW + (BO) + 12288); \
  } while (0)

__global__ __launch_bounds__(512, 2) void gemm256(
    const ushort* __restrict__ X, const ushort* __restrict__ Y,
    float* __restrict__ o32, ushort* __restrict__ o16, int M, int N, int K,
    int mode, const float* __restrict__ theta_p,
    const float* __restrict__ sums) {
  extern __shared__ ushort lds[];  // 3 x (A:8192 | B:8192) ushorts

  const int tid = threadIdx.x;
  const int wave = tid >> 6, lane = tid & 63;

  // T1: XCD-chunked bijective swizzle (nwg = 1024, multiple of 8)
  const int nwg = gridDim.x * gridDim.y;
  const int lin = blockIdx.y * gridDim.x + blockIdx.x;
  const int wgid = (lin & 7) * (nwg >> 3) + (lin >> 3);
  const int bn = wgid & 3;  // gridDim.x == 4 (N = 1024)
  const int bm = wgid >> 2;

  const int wrow = wave >> 2;  // 0..1
  const int wcol = wave & 3;   // 0..3
  const int lr = lane & 15;
  const int kq = (lane >> 4) * 8;  // k-octet within BK=32

  // staging: thread t covers row (t>>2), k-octet (t&3); 2 row-halves each mat
  const ushort* Xs = X + (size_t)(bm * 256 + (tid >> 2)) * K + (tid & 3) * 8;
  const ushort* Ys = Y + (size_t)(bn * 256 + (tid >> 2)) * K + (tid & 3) * 8;
  ushort* stW = lds + wave * 512;  // wave-uniform dest (lane*16B implied)

  // read bases (within a buffer): A at 0, B at 8192 elems
  const ushort* rdA = lds + (wrow * 128 + lr) * 32 + kq;
  const ushort* rdB = lds + 8192 + (wcol * 64 + lr) * 32 + kq;

  f32x4 acc[8][4] = {};

  const int NT = K >> 5;  // 32-wide K-tiles
  int cb = 0;             // compute-buffer elem offset (tile t)
  int sb = 2 * 16384;     // stage-buffer elem offset (tile t+2)

  // prologue: stage tiles 0 and 1; gate tile 0 resident
  STAGE4(0, 0);
  STAGE4(16384, 1);
  asm volatile("s_waitcnt vmcnt(4)" ::: "memory");

  for (int t = 0; t < NT; ++t) {
    SBAR;  // all waves' stages for tile t complete + WAR fence for buf reuse
    if (t + 2 < NT) STAGE4(sb, t + 2);

    bf16x8 af[8], bv[4];
#pragma unroll
    for (int ti = 0; ti < 8; ++ti)
      af[ti] = *(const bf16x8*)(rdA + cb + ti * (16 * 32));
#pragma unroll
    for (int tj = 0; tj < 4; ++tj)
      bv[tj] = *(const bf16x8*)(rdB + cb + tj * (16 * 32));

    __builtin_amdgcn_s_setprio(1);
#pragma unroll
    for (int ti = 0; ti < 8; ++ti)
#pragma unroll
      for (int tj = 0; tj < 4; ++tj)
        acc[ti][tj] = __builtin_amdgcn_mfma_f32_16x16x32_bf16(
            af[ti], bv[tj], acc[ti][tj], 0, 0, 0);
    __builtin_amdgcn_s_setprio(0);

    // gate: complete tile t+1's stages (issued last tile); keep t+2's 4
    // loads in flight. Cross-wave publication = next iteration's SBAR.
    if (t + 2 < NT)
      asm volatile("s_waitcnt vmcnt(4)" ::: "memory");
    else if (t + 1 < NT)
      asm volatile("s_waitcnt vmcnt(0)" ::: "memory");

    cb = (cb == 2 * 16384) ? 0 : cb + 16384;
    sb = (sb == 2 * 16384) ? 0 : sb + 16384;
  }

  // epilogue: C/D layout col = lane&15, row = (lane>>4)*4 + reg
  const int q4 = (lane >> 4) * 4;
  const int rbase = bm * 256 + wrow * 128;
  const int cbase = bn * 256 + wcol * 64;
  if (mode == 1) {
    float th = *theta_p, s, c;
    __sincosf(th, &s, &c);
    const float ssgn = (lane & 1) ? s : -s;
#pragma unroll
    for (int fi = 0; fi < 8; ++fi)
#pragma unroll
      for (int r = 0; r < 4; ++r) {
        const size_t row = (size_t)(rbase + fi * 16 + q4 + r);
        ushort* Orow = o16 + row * N;
#pragma unroll
        for (int fj = 0; fj < 4; ++fj) {
          float v = acc[fi][fj][r];
          float w = __shfl_xor(v, 1);
          Orow[cbase + fj * 16 + lr] = f2bf(c * v + ssgn * w);
        }
      }
  } else {
    const float pt = 1e-6f * (sums[0] * (1.0f / 1048576.0f) +
                              sums[1] * (1.0f / 1048576.0f) + *theta_p);
#pragma unroll
    for (int fi = 0; fi < 8; ++fi)
#pragma unroll
      for (int r = 0; r < 4; ++r) {
        const size_t row = (size_t)(rbase + fi * 16 + q4 + r);
        float* Orow = o32 + row * N;
#pragma unroll
        for (int fj = 0; fj < 4; ++fj)
          Orow[cbase + fj * 16 + lr] = acc[fi][fj][r] + pt;
      }
  }
}

// ---------------------------------------------------------------------------
// BT GEMM (m97 structure) for the small 1024^3 chain. z in {0,1} selects
// matrix (offset mi*MM on X, Y and outputs).
// mode 3: o32 = acc (S1) ; o16 = bf16(-acc) (Bbf);
//         o16b = bf16(I + 2*A - acc) (Gbf), A bf16 via auxb
// mode 4: o16 = bf16(I - auxf + acc) (Fbf), auxf = S1 fp32
// mode 5: o16 = bf16(acc) (Ubf)
// ---------------------------------------------------------------------------
__global__ __launch_bounds__(256, 2) void gemm_bt(
    const ushort* __restrict__ X0, const ushort* __restrict__ Y0,
    float* __restrict__ o32, ushort* __restrict__ o16,
    ushort* __restrict__ o16b, const float* __restrict__ auxf,
    const ushort* __restrict__ auxb, int M, int N, int K, int mode,
    const float* __restrict__ theta_p, const float* __restrict__ sums) {
  __shared__ ushort lA[128 * 32];
  __shared__ ushort lB[128 * 32];

  const int tid = threadIdx.x;
  const int wave = tid >> 6, lane = tid & 63;
  const int mi = blockIdx.z & 1;

  const int nwg = gridDim.x * gridDim.y;
  const int lin = blockIdx.y * gridDim.x + blockIdx.x;
  const int swzb = (lin & 7) * (nwg >> 3) + (lin >> 3);
  const int bn = swzb & 7;  // gridDim.x == 8 always
  const int bm = swzb >> 3;

  const ushort* X = X0 + (size_t)mi * MM;
  const ushort* Y = Y0 + (size_t)mi * MM;

  const ushort* Xg = X + (size_t)(bm * 128 + (tid >> 2)) * K + (tid & 3) * 8;
  const ushort* Yg = Y + (size_t)(bn * 128 + (tid >> 2)) * K + (tid & 3) * 8;
  ushort* lAw = lA + wave * 512;
  ushort* lBw = lB + wave * 512;

  const int wm = (wave & 1) * 64;
  const int wn = (wave >> 1) * 64;
  const int lr = lane & 15;
  const int kq = (lane >> 4) * 8;

  f32x4 acc[4][4] = {};

  for (int k0 = 0; k0 < K; k0 += 32) {
    __syncthreads();
    gld_lds16(Xg + k0, lAw);
    gld_lds16(Xg + k0 + (size_t)64 * K, lAw + 64 * 32);
    gld_lds16(Yg + k0, lBw);
    gld_lds16(Yg + k0 + (size_t)64 * K, lBw + 64 * 32);
    __syncthreads();

    bf16x8 afv[4], bfg[4];
#pragma unroll
    for (int t = 0; t < 4; ++t) {
      afv[t] = *(const bf16x8*)(lA + (wm + t * 16 + lr) * 32 + kq);
      bfg[t] = *(const bf16x8*)(lB + (wn + t * 16 + lr) * 32 + kq);
    }
#pragma unroll
    for (int ti = 0; ti < 4; ++ti)
#pragma unroll
      for (int tj = 0; tj < 4; ++tj)
        acc[ti][tj] = __builtin_amdgcn_mfma_f32_16x16x32_bf16(
            afv[ti], bfg[tj], acc[ti][tj], 0, 0, 0);
  }

  const int q4 = (lane >> 4) * 4;
  const size_t zoff = (size_t)mi * MM;
  float* O = (mode == 3) ? o32 + zoff : nullptr;
  ushort* P0 = o16 + zoff;
  ushort* P1 = (mode == 3) ? o16b + zoff : nullptr;
  const float* Ax = (mode == 4) ? auxf + zoff : nullptr;
  const ushort* Ab = (mode == 3) ? auxb + zoff : nullptr;
#pragma unroll
  for (int ti = 0; ti < 4; ++ti)
#pragma unroll
    for (int r = 0; r < 4; ++r) {
      const int row = bm * 128 + wm + ti * 16 + q4 + r;
      const size_t base = (size_t)row * N;
#pragma unroll
      for (int tj = 0; tj < 4; ++tj) {
        const int col = bn * 128 + wn + tj * 16 + lr;
        const float v = acc[ti][tj][r];
        const float diag = (row == col) ? 1.f : 0.f;
        if (mode == 3) {
          O[base + col] = v;
          P0[base + col] = f2bf(-v);
          P1[base + col] = f2bf(diag + 2.f * bf2f(Ab[base + col]) - v);
        } else if (mode == 4) {
          P0[base + col] = f2bf(diag - Ax[base + col] + v);
        } else {
          P0[base + col] = f2bf(v);
        }
      }
    }
}

// ---------------------------------------------------------------------------
// A = 0.5(W - W^T) -> bf16, fused sum(W) reduction (for passthrough mean).
// ---------------------------------------------------------------------------
__global__ __launch_bounds__(256) void prep_a(const float* __restrict__ W1,
                                              const float* __restrict__ W2,
                                              ushort* __restrict__ Abf,
                                              float* __restrict__ sums) {
  __shared__ float sT[32][33];
  const int z = blockIdx.z;
  const float* W = z ? W2 : W1;
  ushort* A = Abf + (size_t)z * MM;
  const int r0 = blockIdx.y * 32, c0 = blockIdx.x * 32;
  const int x = threadIdx.x, y = threadIdx.y;

#pragma unroll
  for (int k = 0; k < 4; ++k)
    sT[y + 8 * k][x] = W[(size_t)(c0 + y + 8 * k) * 1024 + r0 + x];
  __syncthreads();

  float lsum = 0.f;
#pragma unroll
  for (int k = 0; k < 4; ++k) {
    int i = y + 8 * k;
    float w = W[(size_t)(r0 + i) * 1024 + c0 + x];
    lsum += w;
    A[(size_t)(r0 + i) * 1024 + c0 + x] = f2bf(0.5f * (w - sT[x][i]));
  }
#pragma unroll
  for (int off = 32; off > 0; off >>= 1) lsum += __shfl_down(lsum, off);
  if (((y * 32 + x) & 63) == 0) atomicAdd(&sums[z], lsum);
}

// x fp32 -> bf16, vectorized (float4 per thread)
__global__ __launch_bounds__(256) void cvt_x(const float* __restrict__ x,
                                             ushort* __restrict__ xb) {
  const size_t i = (size_t)blockIdx.x * 256 + threadIdx.x;
  float4 v = ((const float4*)x)[i];
  ushort4 o;
  o.x = f2bf(v.x);
  o.y = f2bf(v.y);
  o.z = f2bf(v.z);
  o.w = f2bf(v.w);
  ((ushort4*)xb)[i] = o;
}

extern "C" void kernel_launch(void* const* d_in, const int* in_sizes, int n_in,
                              void* d_out, int out_size, void* d_ws,
                              size_t ws_size, hipStream_t stream) {
  const float* xin = (const float*)d_in[0];
  const float* w1 = (const float*)d_in[1];
  const float* w2 = (const float*)d_in[2];
  const float* th = (const float*)d_in[3];
  float* out = (float*)d_out;

  // workspace carve (all 256B-aligned)
  char* w = (char*)d_ws;
  float* sums = (float*)w;                   // 8 B
  ushort* Abf = (ushort*)(w + 256);          // 4 MB
  ushort* Bbf = Abf + 2 * MM;                // 4 MB
  ushort* Gbf = Bbf + 2 * MM;                // 4 MB
  ushort* Fbf = Gbf + 2 * MM;                // 4 MB
  ushort* Ubf = Fbf + 2 * MM;                // 4 MB (U1, U2)
  float* S1 = (float*)(Ubf + 2 * MM);        // 8 MB
  ushort* xbf = (ushort*)(S1 + 2 * MM);      // 128 MB
  ushort* hbf = xbf + (size_t)65536 * 1024;  // 128 MB

  static bool inited = false;
  if (!inited) {
    (void)hipFuncSetAttribute((const void*)gemm256,
                              hipFuncAttributeMaxDynamicSharedMemorySize,
                              98304);
    inited = true;
  }

  hipMemsetAsync(sums, 0, 2 * sizeof(float), stream);

  prep_a<<<dim3(32, 32, 2), dim3(32, 8), 0, stream>>>(w1, w2, Abf, sums);
  cvt_x<<<65536, 256, 0, stream>>>(xin, xbf);

  // S1 = A*A^T ; fused: Bbf = bf16(-S1), Gbf = bf16(I + 2A - S1)
  gemm_bt<<<dim3(8, 8, 2), 256, 0, stream>>>(Abf, Abf, S1, Bbf, Gbf, nullptr,
                                             Abf, 1024, 1024, 1024, 3, th,
                                             sums);
  // S2 = B*B^T = B^2 ; fused: Fbf = bf16(I - S1 + S2)
  gemm_bt<<<dim3(8, 8, 2), 256, 0, stream>>>(Bbf, Bbf, nullptr, Fbf, nullptr,
                                             S1, nullptr, 1024, 1024, 1024, 4,
                                             th, sums);
  // U = G*F^T (F symmetric) ; fused: Ubf = bf16(U)
  gemm_bt<<<dim3(8, 8, 2), 256, 0, stream>>>(Gbf, Fbf, nullptr, Ubf, nullptr,
                                             nullptr, nullptr, 1024, 1024,
                                             1024, 5, th, sums);

  // h = rot_theta(x @ U1^T) -> bf16   (3-buffer 1-barrier/K-tile kernel)
  gemm256<<<dim3(4, 256, 1), 512, 98304, stream>>>(
      xbf, Ubf, nullptr, hbf, 65536, 1024, 1024, 1, th, sums);
  // out = h @ U2^T + passthrough -> fp32
  gemm256<<<dim3(4, 256, 1), 512, 98304, stream>>>(
      hbf, Ubf + MM, out, nullptr, 65536, 1024, 1024, 2, th, sums);
}